// Round 3
// baseline (3329.927 us; speedup 1.0000x reference)
//
#include <hip/hip_runtime.h>
#include <cstdint>
#include <cstddef>

#define NPTS    8192
#define NPT     2048      // NPOINT
#define KNB     32        // NSAMPLE
#define NB      4         // batch
#define DPTS    29        // point feature channels
#define CINP    32        // 3 + 29
#define CO      64        // COUT
#define KS      (KNB*NPT)     // 65536 positions per (b, channel)
#define TELEM   ((size_t)NB*CO*KS)  // 16777216 floats per tensor
#define MCNT    262144.0f     // B*K*S for batch-norm
#define BNEPS   1e-5f
#define FPT     32        // FPS points per thread (256 threads x 32 = 8192)

// ---------------------------------------------------------------- FPS
// One block per batch, 256 threads (4 waves), 32 points/thread in registers.
// Strict IEEE sub/mul/add to match the reference's ((dx^2+dy^2)+dz^2);
// argmax with lowest-global-index tie-break (= jnp.argmax first occurrence),
// tracked incrementally inside the update loop (strict > keeps first max).
// out0 accumulated in LDS, flushed once at the end (no global stores, hence
// no vmcnt(0) drain, inside the 2047-iteration barrier loop).
__global__ __launch_bounds__(256, 1) void fps_kernel(const float* __restrict__ xyz,
                                                     float* __restrict__ out0) {
    const int b = blockIdx.x;
    const int t = threadIdx.x;          // 0..255
    const int lane = t & 63;
    const int wid  = t >> 6;            // 0..3
    const float* xb = xyz + (size_t)b * 3 * NPTS;

    float px[FPT], py[FPT], pz[FPT], dist[FPT];
    const int base = t * FPT;           // my first global point index
    {
        const float4* x4 = (const float4*)(xb + base);
        const float4* y4 = (const float4*)(xb + NPTS + base);
        const float4* z4 = (const float4*)(xb + 2 * NPTS + base);
#pragma unroll
        for (int j4 = 0; j4 < FPT / 4; ++j4) {
            float4 vx = x4[j4], vy = y4[j4], vz = z4[j4];
            px[4*j4+0]=vx.x; px[4*j4+1]=vx.y; px[4*j4+2]=vx.z; px[4*j4+3]=vx.w;
            py[4*j4+0]=vy.x; py[4*j4+1]=vy.y; py[4*j4+2]=vy.z; py[4*j4+3]=vy.w;
            pz[4*j4+0]=vz.x; pz[4*j4+1]=vz.y; pz[4*j4+2]=vz.z; pz[4*j4+3]=vz.w;
        }
#pragma unroll
        for (int j = 0; j < FPT; ++j) dist[j] = 1e10f;
    }

    __shared__ float sc[4];           // current centroid
    __shared__ float swm[4];          // per-wave maxes
    __shared__ float so[3][NPT];      // staged out0 (24 KB)

    if (t == 0) {
        sc[0] = px[0]; sc[1] = py[0]; sc[2] = pz[0];
        so[0][0] = px[0]; so[1][0] = py[0]; so[2][0] = pz[0];
    }
    __syncthreads();

    for (int i = 1; i < NPT; ++i) {
        const float cx = sc[0], cy = sc[1], cz = sc[2];
        float tb = -1.0f;
        int   jj = 0;
#pragma unroll
        for (int j = 0; j < FPT; ++j) {
            float dx = __fsub_rn(px[j], cx);
            float dy = __fsub_rn(py[j], cy);
            float dz = __fsub_rn(pz[j], cz);
            float d  = __fadd_rn(__fadd_rn(__fmul_rn(dx, dx), __fmul_rn(dy, dy)),
                                 __fmul_rn(dz, dz));
            float nd = fminf(dist[j], d);
            dist[j] = nd;
            if (nd > tb) { tb = nd; jj = j; }   // strict > keeps FIRST (lowest j) max
        }
        // wave max
        float wm = tb;
#pragma unroll
        for (int o = 32; o > 0; o >>= 1) wm = fmaxf(wm, __shfl_xor(wm, o, 64));
        if (lane == 0) swm[wid] = wm;
        __syncthreads();
        const float m0 = swm[0], m1 = swm[1], m2 = swm[2], m3 = swm[3];
        const float gmax = fmaxf(fmaxf(m0, m1), fmaxf(m2, m3));
        const int wwin = (m0 == gmax) ? 0 : (m1 == gmax) ? 1 : (m2 == gmax) ? 2 : 3;
        if (wid == wwin) {
            unsigned long long lb = __ballot(tb == gmax);
            int lwin = __ffsll((long long)lb) - 1;   // lowest lane = lowest t
            if (lane == lwin) {
                sc[0] = px[jj]; sc[1] = py[jj]; sc[2] = pz[jj];
                so[0][i] = px[jj]; so[1][i] = py[jj]; so[2][i] = pz[jj];
            }
        }
        __syncthreads();
    }

    // flush staged out0 (3,2048) — coalesced
    float* ob = out0 + (size_t)b * 3 * NPT;
    for (int r = t; r < 3 * NPT; r += 256) ob[r] = so[0][r];
}

// ---------------------------------------------------------------- ball query
// One wave per (b, s). 32 smallest in-radius indices (ascending scan +
// ballot compaction), padded with the first hit.
__global__ __launch_bounds__(256) void ballq_kernel(const float* __restrict__ xyz,
                                                    const float* __restrict__ out0,
                                                    int* __restrict__ idx) {
    const int gw   = (blockIdx.x * 256 + threadIdx.x) >> 6;  // 0..8191
    const int lane = threadIdx.x & 63;
    const int b  = gw >> 11;
    const int si = gw & 2047;
    const float* xb = xyz + (size_t)b * 3 * NPTS;

    const float cx = out0[b * 3 * NPT + si];
    const float cy = out0[b * 3 * NPT + NPT + si];
    const float cz = out0[b * 3 * NPT + 2*NPT + si];
    const float csum = __fadd_rn(__fadd_rn(__fmul_rn(cx, cx), __fmul_rn(cy, cy)),
                                 __fmul_rn(cz, cz));
    const float R2 = (float)(0.1 * 0.1);  // 0x3C23D70A — NOT 0.1f*0.1f!

    __shared__ int buf[4][KNB];
    int* mybuf = buf[threadIdx.x >> 6];

    int cnt = 0;
    for (int n0 = 0; n0 < NPTS && cnt < KNB; n0 += 64) {
        const int i = n0 + lane;
        float pxv = xb[i], pyv = xb[NPTS + i], pzv = xb[2 * NPTS + i];
        float ps = __fadd_rn(__fadd_rn(__fmul_rn(pxv, pxv), __fmul_rn(pyv, pyv)),
                             __fmul_rn(pzv, pzv));
        float dot = __fmaf_rn(pzv, cz, __fmaf_rn(pyv, cy, __fmul_rn(pxv, cx)));
        float sqr = __fsub_rn(__fadd_rn(csum, ps), __fadd_rn(dot, dot));
        bool hit = (sqr <= R2);
        unsigned long long m = __ballot(hit);
        int pos = cnt + __popcll(m & ((1ull << lane) - 1ull));
        if (hit && pos < KNB) mybuf[pos] = i;
        cnt += __popcll(m);
    }
    __syncthreads();
    int c = cnt < KNB ? cnt : KNB;
    int first = (cnt > 0) ? mybuf[0] : 0;
    if (lane < KNB) {
        int v = (lane < c) ? mybuf[lane] : first;
        idx[((size_t)gw << 5) + lane] = v;
    }
}

// ---------------------------------------------------------------- proj conv
// Fused gather/concat + conv(32->64) + BN-stats accumulation.
__global__ __launch_bounds__(256) void proj_kernel(const float* __restrict__ xyz,
                                                   const float* __restrict__ points,
                                                   const float* __restrict__ out0,
                                                   const int* __restrict__ idx,
                                                   const float* __restrict__ W,
                                                   float* __restrict__ out,
                                                   float* __restrict__ stats) {
    const int p = blockIdx.x * 256 + threadIdx.x;   // 0..262143
    const int b = p >> 16;
    const int q = p & 65535;       // k*NPT + s
    const int k = q >> 11;
    const int s = q & 2047;
    const int tid = threadIdx.x;

    __shared__ float ssum[CO], ssq[CO];
    if (tid < CO) { ssum[tid] = 0.f; ssq[tid] = 0.f; }
    __syncthreads();

    const int j = idx[((size_t)(b * NPT + s) << 5) + k];
    const float* xb = xyz + (size_t)b * 3 * NPTS;
    float a[CINP];
    a[0] = xb[j]            - out0[b * 3 * NPT + s];
    a[1] = xb[NPTS + j]     - out0[b * 3 * NPT + NPT + s];
    a[2] = xb[2*NPTS + j]   - out0[b * 3 * NPT + 2*NPT + s];
    const float* pb = points + (size_t)b * DPTS * NPTS;
#pragma unroll
    for (int c = 0; c < DPTS; ++c) a[3 + c] = pb[c * NPTS + j];

    const size_t obase = (size_t)b * CO * KS + q;
    for (int o = 0; o < CO; ++o) {
        float acc = 0.f;
#pragma unroll
        for (int c = 0; c < CINP; ++c) acc = __fmaf_rn(W[o * CINP + c], a[c], acc);
        out[obase + (size_t)o * KS] = acc;
        float s1 = acc, s2 = acc * acc;
#pragma unroll
        for (int off = 32; off > 0; off >>= 1) {
            s1 += __shfl_xor(s1, off, 64);
            s2 += __shfl_xor(s2, off, 64);
        }
        if ((tid & 63) == 0) { atomicAdd(&ssum[o], s1); atomicAdd(&ssq[o], s2); }
    }
    __syncthreads();
    if (tid < CO) {
        atomicAdd(&stats[tid], ssum[tid]);
        atomicAdd(&stats[CO + tid], ssq[tid]);
    }
}

// ---------------------------------------------------------------- fused conv
// input-BN (+optional residual) + relu -> GEMM 64x64 -> raw out + stats.
// NOTE: in/idn/act_out/out may ALIAS (in-place use): no __restrict__ on them.
// Safe because each thread touches only its own q-column {base + i*KS}, and
// all its loads (loop 1) precede all its stores of loop 2 in program order.
template <bool HAS_IDN, bool WRITE_ACT>
__global__ __launch_bounds__(256) void conv_bn_kernel(const float* in,
                                                      const float* idn,
                                                      const float* __restrict__ stats_in,
                                                      const float* __restrict__ gamma,
                                                      const float* __restrict__ beta,
                                                      const float* __restrict__ W,
                                                      float* act_out,
                                                      float* out,
                                                      float* __restrict__ stats_out) {
    const int p = blockIdx.x * 256 + threadIdx.x;
    const int b = p >> 16;
    const int q = p & 65535;
    const int tid = threadIdx.x;

    __shared__ float ssc[CO], ssh[CO], ssum[CO], ssq[CO];
    if (tid < CO) {
        const float Minv = 1.0f / MCNT;
        float m = stats_in[tid] * Minv;
        float v = stats_in[CO + tid] * Minv - m * m;
        float scl = gamma[tid] * rsqrtf(v + BNEPS);
        ssc[tid] = scl;
        ssh[tid] = beta[tid] - m * scl;
        ssum[tid] = 0.f; ssq[tid] = 0.f;
    }
    __syncthreads();

    const size_t base = (size_t)b * CO * KS + q;
    float a[CO];
#pragma unroll
    for (int c = 0; c < CO; ++c) {
        float v = __fmaf_rn(ssc[c], in[base + (size_t)c * KS], ssh[c]);
        if (HAS_IDN) v += idn[base + (size_t)c * KS];
        v = fmaxf(v, 0.0f);
        a[c] = v;
        if (WRITE_ACT) act_out[base + (size_t)c * KS] = v;
    }
    for (int o = 0; o < CO; ++o) {
        float acc = 0.f;
#pragma unroll
        for (int c = 0; c < CO; ++c) acc = __fmaf_rn(W[o * CO + c], a[c], acc);
        out[base + (size_t)o * KS] = acc;
        float s1 = acc, s2 = acc * acc;
#pragma unroll
        for (int off = 32; off > 0; off >>= 1) {
            s1 += __shfl_xor(s1, off, 64);
            s2 += __shfl_xor(s2, off, 64);
        }
        if ((tid & 63) == 0) { atomicAdd(&ssum[o], s1); atomicAdd(&ssq[o], s2); }
    }
    __syncthreads();
    if (tid < CO) {
        atomicAdd(&stats_out[tid], ssum[tid]);
        atomicAdd(&stats_out[CO + tid], ssq[tid]);
    }
}

// ---------------------------------------------------------------- final
// BN + residual + relu + maxpool over k.
__global__ __launch_bounds__(256) void final_kernel(const float* __restrict__ y2,
                                                    const float* __restrict__ idn,
                                                    const float* __restrict__ stats,
                                                    const float* __restrict__ gamma,
                                                    const float* __restrict__ beta,
                                                    float* __restrict__ feat) {
    const int p = blockIdx.x * 256 + threadIdx.x;   // 0..524287
    const int s = p & 2047;
    const int o = (p >> 11) & 63;
    const int b = p >> 17;
    const float Minv = 1.0f / MCNT;
    float m = stats[o] * Minv;
    float v = stats[CO + o] * Minv - m * m;
    float scl = gamma[o] * rsqrtf(v + BNEPS);
    float sh  = beta[o] - m * scl;
    const size_t base = (size_t)b * CO * KS + (size_t)o * KS + s;
    float mx = -1e30f;
#pragma unroll
    for (int k = 0; k < KNB; ++k) {
        float val = __fmaf_rn(scl, y2[base + (size_t)k * NPT], sh) + idn[base + (size_t)k * NPT];
        val = fmaxf(val, 0.0f);
        mx = fmaxf(mx, val);
    }
    feat[p] = mx;
}

__global__ void zero_kernel(float* p, int n) {
    int i = blockIdx.x * blockDim.x + threadIdx.x;
    if (i < n) p[i] = 0.f;
}

extern "C" void kernel_launch(void* const* d_in, const int* in_sizes, int n_in,
                              void* d_out, int out_size, void* d_ws, size_t ws_size,
                              hipStream_t stream) {
    (void)in_sizes; (void)n_in; (void)out_size; (void)ws_size;
    const float* xyz    = (const float*)d_in[0];
    const float* points = (const float*)d_in[1];
    const float* proj_w = (const float*)d_in[2];
    const float* proj_g = (const float*)d_in[3];
    const float* proj_b = (const float*)d_in[4];
    const float* w1     = (const float*)d_in[5];   // (2,64,64)
    const float* g1     = (const float*)d_in[6];
    const float* b1     = (const float*)d_in[7];
    const float* w2     = (const float*)d_in[8];
    const float* g2     = (const float*)d_in[9];
    const float* b2     = (const float*)d_in[10];

    float* out0 = (float*)d_out;                   // (4,3,2048)
    float* feat = (float*)d_out + NB * 3 * NPT;    // (4,64,2048)

    // Workspace layout: small arrays first, then TWO big tensors (A, B).
    // Total: (1024 + 262144 + 2*16777216) * 4 B = 135.3 MB.
    float* stats = (float*)d_ws;                    // 5 x 128 (rounded to 1024)
    int*   idx   = (int*)((float*)d_ws + 1024);     // (4,2048,32)
    float* A     = (float*)(idx + NB * NPT * KNB);  // activation tensor
    float* B     = A + TELEM;                       // residual tensor

    hipLaunchKernelGGL(zero_kernel, dim3(3), dim3(256), 0, stream, stats, 5 * 2 * CO);
    hipLaunchKernelGGL(fps_kernel, dim3(NB), dim3(256), 0, stream, xyz, out0);
    hipLaunchKernelGGL(ballq_kernel, dim3(2048), dim3(256), 0, stream, xyz, out0, idx);
    // proj raw conv -> A, stats0
    hipLaunchKernelGGL(proj_kernel, dim3(1024), dim3(256), 0, stream,
                       xyz, points, out0, idx, proj_w, A, stats);
    // d=0: x = relu(bnP(A)); idn0 -> B; y1 -> A (in-place)
    hipLaunchKernelGGL((conv_bn_kernel<false, true>), dim3(1024), dim3(256), 0, stream,
                       A, (const float*)nullptr, stats, proj_g, proj_b, w1,
                       B, A, stats + 128);
    // d=0: y2 = conv(w2[0], relu(bn1(y1)))  A -> A
    hipLaunchKernelGGL((conv_bn_kernel<false, false>), dim3(1024), dim3(256), 0, stream,
                       A, (const float*)nullptr, stats + 128, g1, b1, w2,
                       (float*)nullptr, A, stats + 256);
    // d=1: x = relu(bn2(y2)+idn0); idn1 -> B (aliases idn read); y1 -> A
    hipLaunchKernelGGL((conv_bn_kernel<true, true>), dim3(1024), dim3(256), 0, stream,
                       A, B, stats + 256, g2, b2, w1 + CO * CO,
                       B, A, stats + 384);
    // d=1: y2 = conv(w2[1], relu(bn1'(y1)))  A -> A
    hipLaunchKernelGGL((conv_bn_kernel<false, false>), dim3(1024), dim3(256), 0, stream,
                       A, (const float*)nullptr, stats + 384, g1 + CO, b1 + CO, w2 + CO * CO,
                       (float*)nullptr, A, stats + 512);
    // feat = max_k relu(bn2'(A)+B)
    hipLaunchKernelGGL(final_kernel, dim3(2048), dim3(256), 0, stream,
                       A, B, stats + 512, g2 + CO, b2 + CO, feat);
}

// Round 4
// 2996.107 us; speedup vs baseline: 1.1114x; 1.1114x over previous
//
#include <hip/hip_runtime.h>
#include <cstdint>
#include <cstddef>

#define NPTS    8192
#define NPT     2048      // NPOINT
#define KNB     32        // NSAMPLE
#define NB      4         // batch
#define DPTS    29        // point feature channels
#define CINP    32        // 3 + 29
#define CO      64        // COUT
#define KS      (KNB*NPT)     // 65536 positions per (b, channel)
#define TELEM   ((size_t)NB*CO*KS)  // 16777216 floats per tensor
#define MCNT    262144.0f     // B*K*S for batch-norm
#define BNEPS   1e-5f
#define FTHR    512       // FPS threads
#define FWAVES  (FTHR/64) // 8 waves
#define FPT     (NPTS/FTHR)   // 16 points per thread

// ---------------------------------------------------------------- FPS
// One block per batch, 512 threads (8 waves), 16 points/thread in registers.
// CRITICAL: no dynamic indexing of the point arrays — best-point COORDS are
// carried incrementally (cmp+cndmask), so px/py/pz/dist stay VGPR-resident
// (R3's px[jj] runtime index demoted them to scratch: 108 VGPRs < 128 needed,
// ~3 scratch loads/point/iter -> 2780 us).
// Strict IEEE sub/mul/add matches the reference's ((dx^2+dy^2)+dz^2); strict
// '>' keeps the FIRST max (lowest j); lowest-lane/lowest-wave winner pick
// preserves jnp.argmax first-occurrence semantics (t*FPT+j is monotonic).
__global__ __launch_bounds__(FTHR, 2) void fps_kernel(const float* __restrict__ xyz,
                                                      float* __restrict__ out0) {
    const int b = blockIdx.x;
    const int t = threadIdx.x;          // 0..511
    const int lane = t & 63;
    const int wid  = t >> 6;            // 0..7
    const float* xb = xyz + (size_t)b * 3 * NPTS;

    float px[FPT], py[FPT], pz[FPT], dist[FPT];
    const int base = t * FPT;           // my first global point index
    {
        const float4* x4 = (const float4*)(xb + base);
        const float4* y4 = (const float4*)(xb + NPTS + base);
        const float4* z4 = (const float4*)(xb + 2 * NPTS + base);
#pragma unroll
        for (int j4 = 0; j4 < FPT / 4; ++j4) {
            float4 vx = x4[j4], vy = y4[j4], vz = z4[j4];
            px[4*j4+0]=vx.x; px[4*j4+1]=vx.y; px[4*j4+2]=vx.z; px[4*j4+3]=vx.w;
            py[4*j4+0]=vy.x; py[4*j4+1]=vy.y; py[4*j4+2]=vy.z; py[4*j4+3]=vy.w;
            pz[4*j4+0]=vz.x; pz[4*j4+1]=vz.y; pz[4*j4+2]=vz.z; pz[4*j4+3]=vz.w;
        }
#pragma unroll
        for (int j = 0; j < FPT; ++j) dist[j] = 1e10f;
    }

    __shared__ float sc[4];             // current centroid
    __shared__ float swm[FWAVES];       // per-wave maxes
    __shared__ float so[3][NPT];        // staged out0 (24 KB)

    if (t == 0) {
        sc[0] = px[0]; sc[1] = py[0]; sc[2] = pz[0];
        so[0][0] = px[0]; so[1][0] = py[0]; so[2][0] = pz[0];
    }
    __syncthreads();

    for (int i = 1; i < NPT; ++i) {
        const float cx = sc[0], cy = sc[1], cz = sc[2];
        float tb = -1.0f;
        float bx = 0.f, by = 0.f, bz = 0.f;   // coords of my current best
#pragma unroll
        for (int j = 0; j < FPT; ++j) {
            float dx = __fsub_rn(px[j], cx);
            float dy = __fsub_rn(py[j], cy);
            float dz = __fsub_rn(pz[j], cz);
            float d  = __fadd_rn(__fadd_rn(__fmul_rn(dx, dx), __fmul_rn(dy, dy)),
                                 __fmul_rn(dz, dz));
            float nd = fminf(dist[j], d);
            dist[j] = nd;
            bool gt = (nd > tb);          // strict > keeps FIRST (lowest j) max
            tb = gt ? nd : tb;
            bx = gt ? px[j] : bx;
            by = gt ? py[j] : by;
            bz = gt ? pz[j] : bz;
        }
        // wave max
        float wm = tb;
#pragma unroll
        for (int o = 32; o > 0; o >>= 1) wm = fmaxf(wm, __shfl_xor(wm, o, 64));
        if (lane == 0) swm[wid] = wm;
        __syncthreads();
        // all lanes: global max over the 8 wave-maxes + lowest winning wave
        float m[FWAVES];
#pragma unroll
        for (int w = 0; w < FWAVES; ++w) m[w] = swm[w];
        float gmax = m[0];
#pragma unroll
        for (int w = 1; w < FWAVES; ++w) gmax = fmaxf(gmax, m[w]);
        int wwin = FWAVES - 1;
#pragma unroll
        for (int w = FWAVES - 1; w >= 0; --w) if (m[w] == gmax) wwin = w;  // lowest
        if (wid == wwin) {
            unsigned long long lb = __ballot(tb == gmax);
            int lwin = __ffsll((long long)lb) - 1;   // lowest lane = lowest t
            if (lane == lwin) {
                sc[0] = bx; sc[1] = by; sc[2] = bz;
                so[0][i] = bx; so[1][i] = by; so[2][i] = bz;
            }
        }
        __syncthreads();
    }

    // flush staged out0 (3,2048) — coalesced
    float* ob = out0 + (size_t)b * 3 * NPT;
    for (int r = t; r < 3 * NPT; r += FTHR) ob[r] = so[0][r];
}

// ---------------------------------------------------------------- ball query
// One wave per (b, s). 32 smallest in-radius indices (ascending scan +
// ballot compaction), padded with the first hit.
__global__ __launch_bounds__(256) void ballq_kernel(const float* __restrict__ xyz,
                                                    const float* __restrict__ out0,
                                                    int* __restrict__ idx) {
    const int gw   = (blockIdx.x * 256 + threadIdx.x) >> 6;  // 0..8191
    const int lane = threadIdx.x & 63;
    const int b  = gw >> 11;
    const int si = gw & 2047;
    const float* xb = xyz + (size_t)b * 3 * NPTS;

    const float cx = out0[b * 3 * NPT + si];
    const float cy = out0[b * 3 * NPT + NPT + si];
    const float cz = out0[b * 3 * NPT + 2*NPT + si];
    const float csum = __fadd_rn(__fadd_rn(__fmul_rn(cx, cx), __fmul_rn(cy, cy)),
                                 __fmul_rn(cz, cz));
    const float R2 = (float)(0.1 * 0.1);  // 0x3C23D70A — NOT 0.1f*0.1f!

    __shared__ int buf[4][KNB];
    int* mybuf = buf[threadIdx.x >> 6];

    int cnt = 0;
    for (int n0 = 0; n0 < NPTS && cnt < KNB; n0 += 64) {
        const int i = n0 + lane;
        float pxv = xb[i], pyv = xb[NPTS + i], pzv = xb[2 * NPTS + i];
        float ps = __fadd_rn(__fadd_rn(__fmul_rn(pxv, pxv), __fmul_rn(pyv, pyv)),
                             __fmul_rn(pzv, pzv));
        float dot = __fmaf_rn(pzv, cz, __fmaf_rn(pyv, cy, __fmul_rn(pxv, cx)));
        float sqr = __fsub_rn(__fadd_rn(csum, ps), __fadd_rn(dot, dot));
        bool hit = (sqr <= R2);
        unsigned long long m = __ballot(hit);
        int pos = cnt + __popcll(m & ((1ull << lane) - 1ull));
        if (hit && pos < KNB) mybuf[pos] = i;
        cnt += __popcll(m);
    }
    __syncthreads();
    int c = cnt < KNB ? cnt : KNB;
    int first = (cnt > 0) ? mybuf[0] : 0;
    if (lane < KNB) {
        int v = (lane < c) ? mybuf[lane] : first;
        idx[((size_t)gw << 5) + lane] = v;
    }
}

// ---------------------------------------------------------------- proj conv
// Fused gather/concat + conv(32->64) + BN-stats accumulation.
__global__ __launch_bounds__(256) void proj_kernel(const float* __restrict__ xyz,
                                                   const float* __restrict__ points,
                                                   const float* __restrict__ out0,
                                                   const int* __restrict__ idx,
                                                   const float* __restrict__ W,
                                                   float* __restrict__ out,
                                                   float* __restrict__ stats) {
    const int p = blockIdx.x * 256 + threadIdx.x;   // 0..262143
    const int b = p >> 16;
    const int q = p & 65535;       // k*NPT + s
    const int k = q >> 11;
    const int s = q & 2047;
    const int tid = threadIdx.x;

    __shared__ float ssum[CO], ssq[CO];
    if (tid < CO) { ssum[tid] = 0.f; ssq[tid] = 0.f; }
    __syncthreads();

    const int j = idx[((size_t)(b * NPT + s) << 5) + k];
    const float* xb = xyz + (size_t)b * 3 * NPTS;
    float a[CINP];
    a[0] = xb[j]            - out0[b * 3 * NPT + s];
    a[1] = xb[NPTS + j]     - out0[b * 3 * NPT + NPT + s];
    a[2] = xb[2*NPTS + j]   - out0[b * 3 * NPT + 2*NPT + s];
    const float* pb = points + (size_t)b * DPTS * NPTS;
#pragma unroll
    for (int c = 0; c < DPTS; ++c) a[3 + c] = pb[c * NPTS + j];

    const size_t obase = (size_t)b * CO * KS + q;
    for (int o = 0; o < CO; ++o) {
        float acc = 0.f;
#pragma unroll
        for (int c = 0; c < CINP; ++c) acc = __fmaf_rn(W[o * CINP + c], a[c], acc);
        out[obase + (size_t)o * KS] = acc;
        float s1 = acc, s2 = acc * acc;
#pragma unroll
        for (int off = 32; off > 0; off >>= 1) {
            s1 += __shfl_xor(s1, off, 64);
            s2 += __shfl_xor(s2, off, 64);
        }
        if ((tid & 63) == 0) { atomicAdd(&ssum[o], s1); atomicAdd(&ssq[o], s2); }
    }
    __syncthreads();
    if (tid < CO) {
        atomicAdd(&stats[tid], ssum[tid]);
        atomicAdd(&stats[CO + tid], ssq[tid]);
    }
}

// ---------------------------------------------------------------- fused conv
// input-BN (+optional residual) + relu -> GEMM 64x64 -> raw out + stats.
// NOTE: in/idn/act_out/out may ALIAS (in-place use): no __restrict__ on them.
// Safe because each thread touches only its own q-column {base + i*KS}, and
// all its loads (loop 1) precede all its stores of loop 2 in program order.
template <bool HAS_IDN, bool WRITE_ACT>
__global__ __launch_bounds__(256) void conv_bn_kernel(const float* in,
                                                      const float* idn,
                                                      const float* __restrict__ stats_in,
                                                      const float* __restrict__ gamma,
                                                      const float* __restrict__ beta,
                                                      const float* __restrict__ W,
                                                      float* act_out,
                                                      float* out,
                                                      float* __restrict__ stats_out) {
    const int p = blockIdx.x * 256 + threadIdx.x;
    const int b = p >> 16;
    const int q = p & 65535;
    const int tid = threadIdx.x;

    __shared__ float ssc[CO], ssh[CO], ssum[CO], ssq[CO];
    if (tid < CO) {
        const float Minv = 1.0f / MCNT;
        float m = stats_in[tid] * Minv;
        float v = stats_in[CO + tid] * Minv - m * m;
        float scl = gamma[tid] * rsqrtf(v + BNEPS);
        ssc[tid] = scl;
        ssh[tid] = beta[tid] - m * scl;
        ssum[tid] = 0.f; ssq[tid] = 0.f;
    }
    __syncthreads();

    const size_t base = (size_t)b * CO * KS + q;
    float a[CO];
#pragma unroll
    for (int c = 0; c < CO; ++c) {
        float v = __fmaf_rn(ssc[c], in[base + (size_t)c * KS], ssh[c]);
        if (HAS_IDN) v += idn[base + (size_t)c * KS];
        v = fmaxf(v, 0.0f);
        a[c] = v;
        if (WRITE_ACT) act_out[base + (size_t)c * KS] = v;
    }
    for (int o = 0; o < CO; ++o) {
        float acc = 0.f;
#pragma unroll
        for (int c = 0; c < CO; ++c) acc = __fmaf_rn(W[o * CO + c], a[c], acc);
        out[base + (size_t)o * KS] = acc;
        float s1 = acc, s2 = acc * acc;
#pragma unroll
        for (int off = 32; off > 0; off >>= 1) {
            s1 += __shfl_xor(s1, off, 64);
            s2 += __shfl_xor(s2, off, 64);
        }
        if ((tid & 63) == 0) { atomicAdd(&ssum[o], s1); atomicAdd(&ssq[o], s2); }
    }
    __syncthreads();
    if (tid < CO) {
        atomicAdd(&stats_out[tid], ssum[tid]);
        atomicAdd(&stats_out[CO + tid], ssq[tid]);
    }
}

// ---------------------------------------------------------------- final
// BN + residual + relu + maxpool over k.
__global__ __launch_bounds__(256) void final_kernel(const float* __restrict__ y2,
                                                    const float* __restrict__ idn,
                                                    const float* __restrict__ stats,
                                                    const float* __restrict__ gamma,
                                                    const float* __restrict__ beta,
                                                    float* __restrict__ feat) {
    const int p = blockIdx.x * 256 + threadIdx.x;   // 0..524287
    const int s = p & 2047;
    const int o = (p >> 11) & 63;
    const int b = p >> 17;
    const float Minv = 1.0f / MCNT;
    float m = stats[o] * Minv;
    float v = stats[CO + o] * Minv - m * m;
    float scl = gamma[o] * rsqrtf(v + BNEPS);
    float sh  = beta[o] - m * scl;
    const size_t base = (size_t)b * CO * KS + (size_t)o * KS + s;
    float mx = -1e30f;
#pragma unroll
    for (int k = 0; k < KNB; ++k) {
        float val = __fmaf_rn(scl, y2[base + (size_t)k * NPT], sh) + idn[base + (size_t)k * NPT];
        val = fmaxf(val, 0.0f);
        mx = fmaxf(mx, val);
    }
    feat[p] = mx;
}

__global__ void zero_kernel(float* p, int n) {
    int i = blockIdx.x * blockDim.x + threadIdx.x;
    if (i < n) p[i] = 0.f;
}

extern "C" void kernel_launch(void* const* d_in, const int* in_sizes, int n_in,
                              void* d_out, int out_size, void* d_ws, size_t ws_size,
                              hipStream_t stream) {
    (void)in_sizes; (void)n_in; (void)out_size; (void)ws_size;
    const float* xyz    = (const float*)d_in[0];
    const float* points = (const float*)d_in[1];
    const float* proj_w = (const float*)d_in[2];
    const float* proj_g = (const float*)d_in[3];
    const float* proj_b = (const float*)d_in[4];
    const float* w1     = (const float*)d_in[5];   // (2,64,64)
    const float* g1     = (const float*)d_in[6];
    const float* b1     = (const float*)d_in[7];
    const float* w2     = (const float*)d_in[8];
    const float* g2     = (const float*)d_in[9];
    const float* b2     = (const float*)d_in[10];

    float* out0 = (float*)d_out;                   // (4,3,2048)
    float* feat = (float*)d_out + NB * 3 * NPT;    // (4,64,2048)

    // Workspace layout: small arrays first, then TWO big tensors (A, B).
    // Total: (1024 + 262144 + 2*16777216) * 4 B = 135.3 MB.
    float* stats = (float*)d_ws;                    // 5 x 128 (rounded to 1024)
    int*   idx   = (int*)((float*)d_ws + 1024);     // (4,2048,32)
    float* A     = (float*)(idx + NB * NPT * KNB);  // activation tensor
    float* B     = A + TELEM;                       // residual tensor

    hipLaunchKernelGGL(zero_kernel, dim3(3), dim3(256), 0, stream, stats, 5 * 2 * CO);
    hipLaunchKernelGGL(fps_kernel, dim3(NB), dim3(FTHR), 0, stream, xyz, out0);
    hipLaunchKernelGGL(ballq_kernel, dim3(2048), dim3(256), 0, stream, xyz, out0, idx);
    // proj raw conv -> A, stats0
    hipLaunchKernelGGL(proj_kernel, dim3(1024), dim3(256), 0, stream,
                       xyz, points, out0, idx, proj_w, A, stats);
    // d=0: x = relu(bnP(A)); idn0 -> B; y1 -> A (in-place)
    hipLaunchKernelGGL((conv_bn_kernel<false, true>), dim3(1024), dim3(256), 0, stream,
                       A, (const float*)nullptr, stats, proj_g, proj_b, w1,
                       B, A, stats + 128);
    // d=0: y2 = conv(w2[0], relu(bn1(y1)))  A -> A
    hipLaunchKernelGGL((conv_bn_kernel<false, false>), dim3(1024), dim3(256), 0, stream,
                       A, (const float*)nullptr, stats + 128, g1, b1, w2,
                       (float*)nullptr, A, stats + 256);
    // d=1: x = relu(bn2(y2)+idn0); idn1 -> B (aliases idn read); y1 -> A
    hipLaunchKernelGGL((conv_bn_kernel<true, true>), dim3(1024), dim3(256), 0, stream,
                       A, B, stats + 256, g2, b2, w1 + CO * CO,
                       B, A, stats + 384);
    // d=1: y2 = conv(w2[1], relu(bn1'(y1)))  A -> A
    hipLaunchKernelGGL((conv_bn_kernel<false, false>), dim3(1024), dim3(256), 0, stream,
                       A, (const float*)nullptr, stats + 384, g1 + CO, b1 + CO, w2 + CO * CO,
                       (float*)nullptr, A, stats + 512);
    // feat = max_k relu(bn2'(A)+B)
    hipLaunchKernelGGL(final_kernel, dim3(2048), dim3(256), 0, stream,
                       A, B, stats + 512, g2 + CO, b2 + CO, feat);
}

// Round 5
// 2942.354 us; speedup vs baseline: 1.1317x; 1.0183x over previous
//
#include <hip/hip_runtime.h>
#include <cstdint>
#include <cstddef>

#define NPTS    8192
#define NPT     2048      // NPOINT
#define KNB     32        // NSAMPLE
#define NB      4         // batch
#define DPTS    29        // point feature channels
#define CINP    32        // 3 + 29
#define CO      64        // COUT
#define KS      (KNB*NPT)     // 65536 positions per (b, channel)
#define TELEM   ((size_t)NB*CO*KS)  // 16777216 floats per tensor
#define MCNT    262144.0f     // B*K*S for batch-norm
#define BNEPS   1e-5f
#define FTHR    512       // FPS threads
#define FWAVES  (FTHR/64) // 8 waves
#define FPT     16        // points per thread (512*16 = 8192)

// ---------------------------------------------------------------- FPS
// One block per batch, 512 threads (8 waves), 16 points/thread held in 64
// NAMED SCALARS (no arrays!). R2-R4 evidence: any per-thread array (even
// statically indexed under #pragma unroll) was demoted to scratch by SROA
// (VGPR_Count 40/108/60 vs >=64 needed; ~2850 cyc/iter across all configs,
// VMEM-latency-bound on scratch reloads). Scalars make demotion impossible.
//
// Single barrier per iteration: wave-reduce a 64-bit key
// (dist_bits<<32 | ~gidx) -> lane0 writes skey[parity][wid] -> barrier ->
// all lanes read skey[parity][lane&7], 3-step u64 butterfly -> every lane
// knows the winning point index; coords fetched via same-address broadcast
// global loads (L2-hot). skey double-buffered by parity so no 2nd barrier.
//
// Numerics: strict IEEE sub/mul/add matches np ((dx^2+dy^2)+dz^2); strict
// '>' + ascending j keeps FIRST max; key tie-break (~gidx) picks lowest
// global index => jnp.argmax first-occurrence semantics preserved.
#define FPS_STEP(J)                                                      \
    {                                                                    \
        float dx = __fsub_rn(px##J, cx);                                 \
        float dy = __fsub_rn(py##J, cy);                                 \
        float dz = __fsub_rn(pz##J, cz);                                 \
        float dd = __fadd_rn(__fadd_rn(__fmul_rn(dx, dx),                \
                                       __fmul_rn(dy, dy)),               \
                             __fmul_rn(dz, dz));                         \
        float nd = fminf(d##J, dd);                                      \
        d##J = nd;                                                       \
        bool gt = nd > tb;                                               \
        tb = gt ? nd : tb;                                               \
        jj = gt ? J : jj;                                                \
    }

__global__ __launch_bounds__(FTHR, 2) void fps_kernel(const float* __restrict__ xyz,
                                                      float* __restrict__ out0) {
    const int b = blockIdx.x;
    const int t = threadIdx.x;          // 0..511
    const int lane = t & 63;
    const int wid  = t >> 6;            // 0..7
    const float* xb = xyz + (size_t)b * 3 * NPTS;
    const int base = t * FPT;

    // 64 named scalars — guaranteed VGPR-resident.
    float px0,px1,px2,px3,px4,px5,px6,px7,px8,px9,px10,px11,px12,px13,px14,px15;
    float py0,py1,py2,py3,py4,py5,py6,py7,py8,py9,py10,py11,py12,py13,py14,py15;
    float pz0,pz1,pz2,pz3,pz4,pz5,pz6,pz7,pz8,pz9,pz10,pz11,pz12,pz13,pz14,pz15;
    float d0,d1,d2,d3,d4,d5,d6,d7,d8,d9,d10,d11,d12,d13,d14,d15;
    {
        const float4* x4 = (const float4*)(xb + base);
        const float4* y4 = (const float4*)(xb + NPTS + base);
        const float4* z4 = (const float4*)(xb + 2 * NPTS + base);
        float4 v;
        v = x4[0]; px0 =v.x; px1 =v.y; px2 =v.z; px3 =v.w;
        v = x4[1]; px4 =v.x; px5 =v.y; px6 =v.z; px7 =v.w;
        v = x4[2]; px8 =v.x; px9 =v.y; px10=v.z; px11=v.w;
        v = x4[3]; px12=v.x; px13=v.y; px14=v.z; px15=v.w;
        v = y4[0]; py0 =v.x; py1 =v.y; py2 =v.z; py3 =v.w;
        v = y4[1]; py4 =v.x; py5 =v.y; py6 =v.z; py7 =v.w;
        v = y4[2]; py8 =v.x; py9 =v.y; py10=v.z; py11=v.w;
        v = y4[3]; py12=v.x; py13=v.y; py14=v.z; py15=v.w;
        v = z4[0]; pz0 =v.x; pz1 =v.y; pz2 =v.z; pz3 =v.w;
        v = z4[1]; pz4 =v.x; pz5 =v.y; pz6 =v.z; pz7 =v.w;
        v = z4[2]; pz8 =v.x; pz9 =v.y; pz10=v.z; pz11=v.w;
        v = z4[3]; pz12=v.x; pz13=v.y; pz14=v.z; pz15=v.w;
        d0=d1=d2=d3=d4=d5=d6=d7=d8=d9=d10=d11=d12=d13=d14=d15 = 1e10f;
    }

    __shared__ float so[3][NPT];                     // staged out0 (24 KB)
    __shared__ unsigned long long skey[2][FWAVES];   // double-buffered keys

    // initial centroid = point 0 (broadcast load, all lanes same address)
    float cx = xb[0], cy = xb[NPTS], cz = xb[2 * NPTS];
    if (t == 0) { so[0][0] = cx; so[1][0] = cy; so[2][0] = cz; }
    // no barrier needed: so[][0] is only read at the final flush

    for (int i = 1; i < NPT; ++i) {
        float tb = -1.0f;
        int   jj = 0;
        FPS_STEP(0)  FPS_STEP(1)  FPS_STEP(2)  FPS_STEP(3)
        FPS_STEP(4)  FPS_STEP(5)  FPS_STEP(6)  FPS_STEP(7)
        FPS_STEP(8)  FPS_STEP(9)  FPS_STEP(10) FPS_STEP(11)
        FPS_STEP(12) FPS_STEP(13) FPS_STEP(14) FPS_STEP(15)

        // 64-bit key: larger dist wins; ties -> lower global index (~gidx larger)
        unsigned long long k =
            (((unsigned long long)__float_as_uint(tb)) << 32) |
            (unsigned int)(~(unsigned int)(base + jj));
#pragma unroll
        for (int o = 32; o > 0; o >>= 1) {
            unsigned long long ok = __shfl_xor(k, o, 64);
            k = (ok > k) ? ok : k;
        }
        const int par = i & 1;
        if (lane == 0) skey[par][wid] = k;
        __syncthreads();
        unsigned long long kk = skey[par][lane & (FWAVES - 1)];
#pragma unroll
        for (int o = 1; o < FWAVES; o <<= 1) {
            unsigned long long ok = __shfl_xor(kk, o, 64);
            kk = (ok > kk) ? ok : kk;
        }
        const int widx = (int)(~(unsigned int)kk);   // winning global index
        // broadcast coord fetch (same address across all lanes -> 1 line each)
        cx = xb[widx]; cy = xb[NPTS + widx]; cz = xb[2 * NPTS + widx];
        if (t == 0) { so[0][i] = cx; so[1][i] = cy; so[2][i] = cz; }
        // no 2nd barrier: skey is parity double-buffered; so[][i] write-once
    }

    __syncthreads();
    // flush staged out0 (3,2048) — coalesced
    float* ob = out0 + (size_t)b * 3 * NPT;
    for (int r = t; r < 3 * NPT; r += FTHR) ob[r] = so[0][r];
}

// ---------------------------------------------------------------- ball query
// One wave per (b, s). 32 smallest in-radius indices (ascending scan +
// ballot compaction), padded with the first hit.
__global__ __launch_bounds__(256) void ballq_kernel(const float* __restrict__ xyz,
                                                    const float* __restrict__ out0,
                                                    int* __restrict__ idx) {
    const int gw   = (blockIdx.x * 256 + threadIdx.x) >> 6;  // 0..8191
    const int lane = threadIdx.x & 63;
    const int b  = gw >> 11;
    const int si = gw & 2047;
    const float* xb = xyz + (size_t)b * 3 * NPTS;

    const float cx = out0[b * 3 * NPT + si];
    const float cy = out0[b * 3 * NPT + NPT + si];
    const float cz = out0[b * 3 * NPT + 2*NPT + si];
    const float csum = __fadd_rn(__fadd_rn(__fmul_rn(cx, cx), __fmul_rn(cy, cy)),
                                 __fmul_rn(cz, cz));
    const float R2 = (float)(0.1 * 0.1);  // 0x3C23D70A — NOT 0.1f*0.1f!

    __shared__ int buf[4][KNB];
    int* mybuf = buf[threadIdx.x >> 6];

    int cnt = 0;
    for (int n0 = 0; n0 < NPTS && cnt < KNB; n0 += 64) {
        const int i = n0 + lane;
        float pxv = xb[i], pyv = xb[NPTS + i], pzv = xb[2 * NPTS + i];
        float ps = __fadd_rn(__fadd_rn(__fmul_rn(pxv, pxv), __fmul_rn(pyv, pyv)),
                             __fmul_rn(pzv, pzv));
        float dot = __fmaf_rn(pzv, cz, __fmaf_rn(pyv, cy, __fmul_rn(pxv, cx)));
        float sqr = __fsub_rn(__fadd_rn(csum, ps), __fadd_rn(dot, dot));
        bool hit = (sqr <= R2);
        unsigned long long m = __ballot(hit);
        int pos = cnt + __popcll(m & ((1ull << lane) - 1ull));
        if (hit && pos < KNB) mybuf[pos] = i;
        cnt += __popcll(m);
    }
    __syncthreads();
    int c = cnt < KNB ? cnt : KNB;
    int first = (cnt > 0) ? mybuf[0] : 0;
    if (lane < KNB) {
        int v = (lane < c) ? mybuf[lane] : first;
        idx[((size_t)gw << 5) + lane] = v;
    }
}

// ---------------------------------------------------------------- proj conv
// Fused gather/concat + conv(32->64) + BN-stats accumulation.
__global__ __launch_bounds__(256) void proj_kernel(const float* __restrict__ xyz,
                                                   const float* __restrict__ points,
                                                   const float* __restrict__ out0,
                                                   const int* __restrict__ idx,
                                                   const float* __restrict__ W,
                                                   float* __restrict__ out,
                                                   float* __restrict__ stats) {
    const int p = blockIdx.x * 256 + threadIdx.x;   // 0..262143
    const int b = p >> 16;
    const int q = p & 65535;       // k*NPT + s
    const int k = q >> 11;
    const int s = q & 2047;
    const int tid = threadIdx.x;

    __shared__ float ssum[CO], ssq[CO];
    if (tid < CO) { ssum[tid] = 0.f; ssq[tid] = 0.f; }
    __syncthreads();

    const int j = idx[((size_t)(b * NPT + s) << 5) + k];
    const float* xb = xyz + (size_t)b * 3 * NPTS;
    float a[CINP];
    a[0] = xb[j]            - out0[b * 3 * NPT + s];
    a[1] = xb[NPTS + j]     - out0[b * 3 * NPT + NPT + s];
    a[2] = xb[2*NPTS + j]   - out0[b * 3 * NPT + 2*NPT + s];
    const float* pb = points + (size_t)b * DPTS * NPTS;
#pragma unroll
    for (int c = 0; c < DPTS; ++c) a[3 + c] = pb[c * NPTS + j];

    const size_t obase = (size_t)b * CO * KS + q;
    for (int o = 0; o < CO; ++o) {
        float acc = 0.f;
#pragma unroll
        for (int c = 0; c < CINP; ++c) acc = __fmaf_rn(W[o * CINP + c], a[c], acc);
        out[obase + (size_t)o * KS] = acc;
        float s1 = acc, s2 = acc * acc;
#pragma unroll
        for (int off = 32; off > 0; off >>= 1) {
            s1 += __shfl_xor(s1, off, 64);
            s2 += __shfl_xor(s2, off, 64);
        }
        if ((tid & 63) == 0) { atomicAdd(&ssum[o], s1); atomicAdd(&ssq[o], s2); }
    }
    __syncthreads();
    if (tid < CO) {
        atomicAdd(&stats[tid], ssum[tid]);
        atomicAdd(&stats[CO + tid], ssq[tid]);
    }
}

// ---------------------------------------------------------------- fused conv
// input-BN (+optional residual) + relu -> GEMM 64x64 -> raw out + stats.
// NOTE: in/idn/act_out/out may ALIAS (in-place use): no __restrict__ on them.
// Safe because each thread touches only its own q-column {base + i*KS}, and
// all its loads (loop 1) precede all its stores of loop 2 in program order.
template <bool HAS_IDN, bool WRITE_ACT>
__global__ __launch_bounds__(256) void conv_bn_kernel(const float* in,
                                                      const float* idn,
                                                      const float* __restrict__ stats_in,
                                                      const float* __restrict__ gamma,
                                                      const float* __restrict__ beta,
                                                      const float* __restrict__ W,
                                                      float* act_out,
                                                      float* out,
                                                      float* __restrict__ stats_out) {
    const int p = blockIdx.x * 256 + threadIdx.x;
    const int b = p >> 16;
    const int q = p & 65535;
    const int tid = threadIdx.x;

    __shared__ float ssc[CO], ssh[CO], ssum[CO], ssq[CO];
    if (tid < CO) {
        const float Minv = 1.0f / MCNT;
        float m = stats_in[tid] * Minv;
        float v = stats_in[CO + tid] * Minv - m * m;
        float scl = gamma[tid] * rsqrtf(v + BNEPS);
        ssc[tid] = scl;
        ssh[tid] = beta[tid] - m * scl;
        ssum[tid] = 0.f; ssq[tid] = 0.f;
    }
    __syncthreads();

    const size_t base = (size_t)b * CO * KS + q;
    float a[CO];
#pragma unroll
    for (int c = 0; c < CO; ++c) {
        float v = __fmaf_rn(ssc[c], in[base + (size_t)c * KS], ssh[c]);
        if (HAS_IDN) v += idn[base + (size_t)c * KS];
        v = fmaxf(v, 0.0f);
        a[c] = v;
        if (WRITE_ACT) act_out[base + (size_t)c * KS] = v;
    }
    for (int o = 0; o < CO; ++o) {
        float acc = 0.f;
#pragma unroll
        for (int c = 0; c < CO; ++c) acc = __fmaf_rn(W[o * CO + c], a[c], acc);
        out[base + (size_t)o * KS] = acc;
        float s1 = acc, s2 = acc * acc;
#pragma unroll
        for (int off = 32; off > 0; off >>= 1) {
            s1 += __shfl_xor(s1, off, 64);
            s2 += __shfl_xor(s2, off, 64);
        }
        if ((tid & 63) == 0) { atomicAdd(&ssum[o], s1); atomicAdd(&ssq[o], s2); }
    }
    __syncthreads();
    if (tid < CO) {
        atomicAdd(&stats_out[tid], ssum[tid]);
        atomicAdd(&stats_out[CO + tid], ssq[tid]);
    }
}

// ---------------------------------------------------------------- final
// BN + residual + relu + maxpool over k.
__global__ __launch_bounds__(256) void final_kernel(const float* __restrict__ y2,
                                                    const float* __restrict__ idn,
                                                    const float* __restrict__ stats,
                                                    const float* __restrict__ gamma,
                                                    const float* __restrict__ beta,
                                                    float* __restrict__ feat) {
    const int p = blockIdx.x * 256 + threadIdx.x;   // 0..524287
    const int s = p & 2047;
    const int o = (p >> 11) & 63;
    const int b = p >> 17;
    const float Minv = 1.0f / MCNT;
    float m = stats[o] * Minv;
    float v = stats[CO + o] * Minv - m * m;
    float scl = gamma[o] * rsqrtf(v + BNEPS);
    float sh  = beta[o] - m * scl;
    const size_t base = (size_t)b * CO * KS + (size_t)o * KS + s;
    float mx = -1e30f;
#pragma unroll
    for (int k = 0; k < KNB; ++k) {
        float val = __fmaf_rn(scl, y2[base + (size_t)k * NPT], sh) + idn[base + (size_t)k * NPT];
        val = fmaxf(val, 0.0f);
        mx = fmaxf(mx, val);
    }
    feat[p] = mx;
}

__global__ void zero_kernel(float* p, int n) {
    int i = blockIdx.x * blockDim.x + threadIdx.x;
    if (i < n) p[i] = 0.f;
}

extern "C" void kernel_launch(void* const* d_in, const int* in_sizes, int n_in,
                              void* d_out, int out_size, void* d_ws, size_t ws_size,
                              hipStream_t stream) {
    (void)in_sizes; (void)n_in; (void)out_size; (void)ws_size;
    const float* xyz    = (const float*)d_in[0];
    const float* points = (const float*)d_in[1];
    const float* proj_w = (const float*)d_in[2];
    const float* proj_g = (const float*)d_in[3];
    const float* proj_b = (const float*)d_in[4];
    const float* w1     = (const float*)d_in[5];   // (2,64,64)
    const float* g1     = (const float*)d_in[6];
    const float* b1     = (const float*)d_in[7];
    const float* w2     = (const float*)d_in[8];
    const float* g2     = (const float*)d_in[9];
    const float* b2     = (const float*)d_in[10];

    float* out0 = (float*)d_out;                   // (4,3,2048)
    float* feat = (float*)d_out + NB * 3 * NPT;    // (4,64,2048)

    // Workspace layout: small arrays first, then TWO big tensors (A, B).
    // Total: (1024 + 262144 + 2*16777216) * 4 B = 135.3 MB.
    float* stats = (float*)d_ws;                    // 5 x 128 (rounded to 1024)
    int*   idx   = (int*)((float*)d_ws + 1024);     // (4,2048,32)
    float* A     = (float*)(idx + NB * NPT * KNB);  // activation tensor
    float* B     = A + TELEM;                       // residual tensor

    hipLaunchKernelGGL(zero_kernel, dim3(3), dim3(256), 0, stream, stats, 5 * 2 * CO);
    hipLaunchKernelGGL(fps_kernel, dim3(NB), dim3(FTHR), 0, stream, xyz, out0);
    hipLaunchKernelGGL(ballq_kernel, dim3(2048), dim3(256), 0, stream, xyz, out0, idx);
    // proj raw conv -> A, stats0
    hipLaunchKernelGGL(proj_kernel, dim3(1024), dim3(256), 0, stream,
                       xyz, points, out0, idx, proj_w, A, stats);
    // d=0: x = relu(bnP(A)); idn0 -> B; y1 -> A (in-place)
    hipLaunchKernelGGL((conv_bn_kernel<false, true>), dim3(1024), dim3(256), 0, stream,
                       A, (const float*)nullptr, stats, proj_g, proj_b, w1,
                       B, A, stats + 128);
    // d=0: y2 = conv(w2[0], relu(bn1(y1)))  A -> A
    hipLaunchKernelGGL((conv_bn_kernel<false, false>), dim3(1024), dim3(256), 0, stream,
                       A, (const float*)nullptr, stats + 128, g1, b1, w2,
                       (float*)nullptr, A, stats + 256);
    // d=1: x = relu(bn2(y2)+idn0); idn1 -> B (aliases idn read); y1 -> A
    hipLaunchKernelGGL((conv_bn_kernel<true, true>), dim3(1024), dim3(256), 0, stream,
                       A, B, stats + 256, g2, b2, w1 + CO * CO,
                       B, A, stats + 384);
    // d=1: y2 = conv(w2[1], relu(bn1'(y1)))  A -> A
    hipLaunchKernelGGL((conv_bn_kernel<false, false>), dim3(1024), dim3(256), 0, stream,
                       A, (const float*)nullptr, stats + 384, g1 + CO, b1 + CO, w2 + CO * CO,
                       (float*)nullptr, A, stats + 512);
    // feat = max_k relu(bn2'(A)+B)
    hipLaunchKernelGGL(final_kernel, dim3(2048), dim3(256), 0, stream,
                       A, B, stats + 512, g2 + CO, b2 + CO, feat);
}

// Round 6
// 2757.439 us; speedup vs baseline: 1.2076x; 1.0671x over previous
//
#include <hip/hip_runtime.h>
#include <cstdint>
#include <cstddef>

#define NPTS    8192
#define NPT     2048      // NPOINT
#define KNB     32        // NSAMPLE
#define NB      4         // batch
#define DPTS    29        // point feature channels
#define CINP    32        // 3 + 29
#define CO      64        // COUT
#define KS      (KNB*NPT)     // 65536 positions per (b, channel)
#define TELEM   ((size_t)NB*CO*KS)  // 16777216 floats per tensor
#define MCNT    262144.0f     // B*K*S for batch-norm
#define BNEPS   1e-5f
#define FTHR    512       // FPS threads
#define FWAVES  (FTHR/64) // 8 waves
#define FPT     16        // points per thread (512*16 = 8192)

// ---------------------------------------------------------------- FPS
// One block per batch, 512 threads. Evidence through R5: ~2770 cyc/iter =
// ~1550 VALU-issue + ~1200 reduce-tail latency. This round attacks the tail:
//  * wave reduce on f32 (6x 1-bpermute butterfly) + ballot + one 32b shfl,
//    instead of u64 butterfly (6x 2 bpermutes).
//  * block reduce: 4x ds_read_b128 of the 8 wave keys + register max-tree,
//    instead of LDS + 3-step u64 butterfly.
//  * centroid coords from an LDS copy of the cloud (broadcast ds_read),
//    instead of global loads.
//  * winner coords stored to out0 directly by t0 (fire-and-forget).
// Numerics: strict IEEE sub/mul/add matches np ((dx^2+dy^2)+dz^2); strict
// '>' + ascending j keeps FIRST max in-thread; lowest-lane ballot pick =
// lowest gidx (ownership monotonic in t); u64 keys (dist||~gidx) across
// waves => jnp.argmax first-occurrence semantics exact.
#define FPS_STEP(J)                                                      \
    {                                                                    \
        float dx = __fsub_rn(px##J, cx);                                 \
        float dy = __fsub_rn(py##J, cy);                                 \
        float dz = __fsub_rn(pz##J, cz);                                 \
        float dd = __fadd_rn(__fadd_rn(__fmul_rn(dx, dx),                \
                                       __fmul_rn(dy, dy)),               \
                             __fmul_rn(dz, dz));                         \
        float nd = fminf(d##J, dd);                                      \
        d##J = nd;                                                       \
        bool gt = nd > tb;                                               \
        tb = gt ? nd : tb;                                               \
        jj = gt ? J : jj;                                                \
    }

static __device__ __forceinline__ unsigned long long umax64(unsigned long long a,
                                                            unsigned long long b) {
    return a > b ? a : b;
}

__global__ __launch_bounds__(FTHR) void fps_kernel(const float* __restrict__ xyz,
                                                   float* __restrict__ out0) {
    const int b = blockIdx.x;
    const int t = threadIdx.x;          // 0..511
    const int lane = t & 63;
    const int wid  = t >> 6;            // 0..7
    const float* xb = xyz + (size_t)b * 3 * NPTS;
    const int base = t * FPT;

    // dynamic LDS: sx/sy/sz cloud copy (96 KB) + skey[2][8] (128 B)
    extern __shared__ float smem[];
    float* sx = smem;
    float* sy = sx + NPTS;
    float* sz = sy + NPTS;
    unsigned long long* skey = (unsigned long long*)(sz + NPTS); // [2][8], 16B-aligned

    // 64 named scalars for the point set + running distances.
    float px0,px1,px2,px3,px4,px5,px6,px7,px8,px9,px10,px11,px12,px13,px14,px15;
    float py0,py1,py2,py3,py4,py5,py6,py7,py8,py9,py10,py11,py12,py13,py14,py15;
    float pz0,pz1,pz2,pz3,pz4,pz5,pz6,pz7,pz8,pz9,pz10,pz11,pz12,pz13,pz14,pz15;
    float d0,d1,d2,d3,d4,d5,d6,d7,d8,d9,d10,d11,d12,d13,d14,d15;
    {
        const float4* x4 = (const float4*)(xb + base);
        const float4* y4 = (const float4*)(xb + NPTS + base);
        const float4* z4 = (const float4*)(xb + 2 * NPTS + base);
        float4* lx4 = (float4*)(sx + base);
        float4* ly4 = (float4*)(sy + base);
        float4* lz4 = (float4*)(sz + base);
        float4 v;
        v = x4[0]; lx4[0] = v; px0 =v.x; px1 =v.y; px2 =v.z; px3 =v.w;
        v = x4[1]; lx4[1] = v; px4 =v.x; px5 =v.y; px6 =v.z; px7 =v.w;
        v = x4[2]; lx4[2] = v; px8 =v.x; px9 =v.y; px10=v.z; px11=v.w;
        v = x4[3]; lx4[3] = v; px12=v.x; px13=v.y; px14=v.z; px15=v.w;
        v = y4[0]; ly4[0] = v; py0 =v.x; py1 =v.y; py2 =v.z; py3 =v.w;
        v = y4[1]; ly4[1] = v; py4 =v.x; py5 =v.y; py6 =v.z; py7 =v.w;
        v = y4[2]; ly4[2] = v; py8 =v.x; py9 =v.y; py10=v.z; py11=v.w;
        v = y4[3]; ly4[3] = v; py12=v.x; py13=v.y; py14=v.z; py15=v.w;
        v = z4[0]; lz4[0] = v; pz0 =v.x; pz1 =v.y; pz2 =v.z; pz3 =v.w;
        v = z4[1]; lz4[1] = v; pz4 =v.x; pz5 =v.y; pz6 =v.z; pz7 =v.w;
        v = z4[2]; lz4[2] = v; pz8 =v.x; pz9 =v.y; pz10=v.z; pz11=v.w;
        v = z4[3]; lz4[3] = v; pz12=v.x; pz13=v.y; pz14=v.z; pz15=v.w;
        d0=d1=d2=d3=d4=d5=d6=d7=d8=d9=d10=d11=d12=d13=d14=d15 = 1e10f;
    }

    // initial centroid = point 0 (broadcast global load; LDS copy not yet synced)
    float cx = xb[0], cy = xb[NPTS], cz = xb[2 * NPTS];
    float* ob = out0 + (size_t)b * 3 * NPT;
    if (t == 0) { ob[0] = cx; ob[NPT] = cy; ob[2 * NPT] = cz; }

    for (int i = 1; i < NPT; ++i) {
        float tb = -1.0f;
        int   jj = 0;
        FPS_STEP(0)  FPS_STEP(1)  FPS_STEP(2)  FPS_STEP(3)
        FPS_STEP(4)  FPS_STEP(5)  FPS_STEP(6)  FPS_STEP(7)
        FPS_STEP(8)  FPS_STEP(9)  FPS_STEP(10) FPS_STEP(11)
        FPS_STEP(12) FPS_STEP(13) FPS_STEP(14) FPS_STEP(15)
        const int gidx = base + jj;

        // wave max on f32 (1 bpermute per step)
        float wm = tb;
#pragma unroll
        for (int o = 32; o > 0; o >>= 1) wm = fmaxf(wm, __shfl_xor(wm, o, 64));
        // winner lane = lowest lane holding wm (= lowest gidx within wave)
        unsigned long long eq = __ballot(tb == wm);
        const int lwin = __ffsll((long long)eq) - 1;
        const int wgid = __shfl(gidx, lwin, 64);

        const int par = i & 1;
        if (lane == 0)
            skey[par * FWAVES + wid] =
                (((unsigned long long)__float_as_uint(wm)) << 32) |
                (unsigned int)(~(unsigned int)wgid);
        __syncthreads();

        // block reduce: read all 8 wave keys, register max-tree
        const ulonglong2* sk2 = (const ulonglong2*)(skey + par * FWAVES);
        ulonglong2 k01 = sk2[0], k23 = sk2[1], k45 = sk2[2], k67 = sk2[3];
        unsigned long long ka = umax64(k01.x, k01.y);
        unsigned long long kb = umax64(k23.x, k23.y);
        unsigned long long kc = umax64(k45.x, k45.y);
        unsigned long long kd = umax64(k67.x, k67.y);
        unsigned long long kbest = umax64(umax64(ka, kb), umax64(kc, kd));
        const int widx = (int)(~(unsigned int)kbest);

        // broadcast coord fetch from LDS cloud copy
        cx = sx[widx]; cy = sy[widx]; cz = sz[widx];
        if (t == 0) { ob[i] = cx; ob[NPT + i] = cy; ob[2 * NPT + i] = cz; }
        // no 2nd barrier: skey parity double-buffered (see R5 proof)
    }
}

// ---------------------------------------------------------------- ball query
// One wave per (b, s). 32 smallest in-radius indices (ascending scan +
// ballot compaction), padded with the first hit.
__global__ __launch_bounds__(256) void ballq_kernel(const float* __restrict__ xyz,
                                                    const float* __restrict__ out0,
                                                    int* __restrict__ idx) {
    const int gw   = (blockIdx.x * 256 + threadIdx.x) >> 6;  // 0..8191
    const int lane = threadIdx.x & 63;
    const int b  = gw >> 11;
    const int si = gw & 2047;
    const float* xb = xyz + (size_t)b * 3 * NPTS;

    const float cx = out0[b * 3 * NPT + si];
    const float cy = out0[b * 3 * NPT + NPT + si];
    const float cz = out0[b * 3 * NPT + 2*NPT + si];
    const float csum = __fadd_rn(__fadd_rn(__fmul_rn(cx, cx), __fmul_rn(cy, cy)),
                                 __fmul_rn(cz, cz));
    const float R2 = (float)(0.1 * 0.1);  // 0x3C23D70A — NOT 0.1f*0.1f!

    __shared__ int buf[4][KNB];
    int* mybuf = buf[threadIdx.x >> 6];

    int cnt = 0;
    for (int n0 = 0; n0 < NPTS && cnt < KNB; n0 += 64) {
        const int i = n0 + lane;
        float pxv = xb[i], pyv = xb[NPTS + i], pzv = xb[2 * NPTS + i];
        float ps = __fadd_rn(__fadd_rn(__fmul_rn(pxv, pxv), __fmul_rn(pyv, pyv)),
                             __fmul_rn(pzv, pzv));
        float dot = __fmaf_rn(pzv, cz, __fmaf_rn(pyv, cy, __fmul_rn(pxv, cx)));
        float sqr = __fsub_rn(__fadd_rn(csum, ps), __fadd_rn(dot, dot));
        bool hit = (sqr <= R2);
        unsigned long long m = __ballot(hit);
        int pos = cnt + __popcll(m & ((1ull << lane) - 1ull));
        if (hit && pos < KNB) mybuf[pos] = i;
        cnt += __popcll(m);
    }
    __syncthreads();
    int c = cnt < KNB ? cnt : KNB;
    int first = (cnt > 0) ? mybuf[0] : 0;
    if (lane < KNB) {
        int v = (lane < c) ? mybuf[lane] : first;
        idx[((size_t)gw << 5) + lane] = v;
    }
}

// ---------------------------------------------------------------- proj conv
// Fused gather/concat + conv(32->64) + BN-stats accumulation.
__global__ __launch_bounds__(256) void proj_kernel(const float* __restrict__ xyz,
                                                   const float* __restrict__ points,
                                                   const float* __restrict__ out0,
                                                   const int* __restrict__ idx,
                                                   const float* __restrict__ W,
                                                   float* __restrict__ out,
                                                   float* __restrict__ stats) {
    const int p = blockIdx.x * 256 + threadIdx.x;   // 0..262143
    const int b = p >> 16;
    const int q = p & 65535;       // k*NPT + s
    const int k = q >> 11;
    const int s = q & 2047;
    const int tid = threadIdx.x;

    __shared__ float ssum[CO], ssq[CO];
    if (tid < CO) { ssum[tid] = 0.f; ssq[tid] = 0.f; }
    __syncthreads();

    const int j = idx[((size_t)(b * NPT + s) << 5) + k];
    const float* xb = xyz + (size_t)b * 3 * NPTS;
    float a[CINP];
    a[0] = xb[j]            - out0[b * 3 * NPT + s];
    a[1] = xb[NPTS + j]     - out0[b * 3 * NPT + NPT + s];
    a[2] = xb[2*NPTS + j]   - out0[b * 3 * NPT + 2*NPT + s];
    const float* pb = points + (size_t)b * DPTS * NPTS;
#pragma unroll
    for (int c = 0; c < DPTS; ++c) a[3 + c] = pb[c * NPTS + j];

    const size_t obase = (size_t)b * CO * KS + q;
    for (int o = 0; o < CO; ++o) {
        float acc = 0.f;
#pragma unroll
        for (int c = 0; c < CINP; ++c) acc = __fmaf_rn(W[o * CINP + c], a[c], acc);
        out[obase + (size_t)o * KS] = acc;
        float s1 = acc, s2 = acc * acc;
#pragma unroll
        for (int off = 32; off > 0; off >>= 1) {
            s1 += __shfl_xor(s1, off, 64);
            s2 += __shfl_xor(s2, off, 64);
        }
        if ((tid & 63) == 0) { atomicAdd(&ssum[o], s1); atomicAdd(&ssq[o], s2); }
    }
    __syncthreads();
    if (tid < CO) {
        atomicAdd(&stats[tid], ssum[tid]);
        atomicAdd(&stats[CO + tid], ssq[tid]);
    }
}

// ---------------------------------------------------------------- fused conv
// input-BN (+optional residual) + relu -> GEMM 64x64 -> raw out + stats.
// NOTE: in/idn/act_out/out may ALIAS (in-place use): no __restrict__ on them.
// Safe because each thread touches only its own q-column {base + i*KS}, and
// all its loads (loop 1) precede all its stores of loop 2 in program order.
template <bool HAS_IDN, bool WRITE_ACT>
__global__ __launch_bounds__(256) void conv_bn_kernel(const float* in,
                                                      const float* idn,
                                                      const float* __restrict__ stats_in,
                                                      const float* __restrict__ gamma,
                                                      const float* __restrict__ beta,
                                                      const float* __restrict__ W,
                                                      float* act_out,
                                                      float* out,
                                                      float* __restrict__ stats_out) {
    const int p = blockIdx.x * 256 + threadIdx.x;
    const int b = p >> 16;
    const int q = p & 65535;
    const int tid = threadIdx.x;

    __shared__ float ssc[CO], ssh[CO], ssum[CO], ssq[CO];
    if (tid < CO) {
        const float Minv = 1.0f / MCNT;
        float m = stats_in[tid] * Minv;
        float v = stats_in[CO + tid] * Minv - m * m;
        float scl = gamma[tid] * rsqrtf(v + BNEPS);
        ssc[tid] = scl;
        ssh[tid] = beta[tid] - m * scl;
        ssum[tid] = 0.f; ssq[tid] = 0.f;
    }
    __syncthreads();

    const size_t base = (size_t)b * CO * KS + q;
    float a[CO];
#pragma unroll
    for (int c = 0; c < CO; ++c) {
        float v = __fmaf_rn(ssc[c], in[base + (size_t)c * KS], ssh[c]);
        if (HAS_IDN) v += idn[base + (size_t)c * KS];
        v = fmaxf(v, 0.0f);
        a[c] = v;
        if (WRITE_ACT) act_out[base + (size_t)c * KS] = v;
    }
    for (int o = 0; o < CO; ++o) {
        float acc = 0.f;
#pragma unroll
        for (int c = 0; c < CO; ++c) acc = __fmaf_rn(W[o * CO + c], a[c], acc);
        out[base + (size_t)o * KS] = acc;
        float s1 = acc, s2 = acc * acc;
#pragma unroll
        for (int off = 32; off > 0; off >>= 1) {
            s1 += __shfl_xor(s1, off, 64);
            s2 += __shfl_xor(s2, off, 64);
        }
        if ((tid & 63) == 0) { atomicAdd(&ssum[o], s1); atomicAdd(&ssq[o], s2); }
    }
    __syncthreads();
    if (tid < CO) {
        atomicAdd(&stats_out[tid], ssum[tid]);
        atomicAdd(&stats_out[CO + tid], ssq[tid]);
    }
}

// ---------------------------------------------------------------- final
// BN + residual + relu + maxpool over k.
__global__ __launch_bounds__(256) void final_kernel(const float* __restrict__ y2,
                                                    const float* __restrict__ idn,
                                                    const float* __restrict__ stats,
                                                    const float* __restrict__ gamma,
                                                    const float* __restrict__ beta,
                                                    float* __restrict__ feat) {
    const int p = blockIdx.x * 256 + threadIdx.x;   // 0..524287
    const int s = p & 2047;
    const int o = (p >> 11) & 63;
    const int b = p >> 17;
    const float Minv = 1.0f / MCNT;
    float m = stats[o] * Minv;
    float v = stats[CO + o] * Minv - m * m;
    float scl = gamma[o] * rsqrtf(v + BNEPS);
    float sh  = beta[o] - m * scl;
    const size_t base = (size_t)b * CO * KS + (size_t)o * KS + s;
    float mx = -1e30f;
#pragma unroll
    for (int k = 0; k < KNB; ++k) {
        float val = __fmaf_rn(scl, y2[base + (size_t)k * NPT], sh) + idn[base + (size_t)k * NPT];
        val = fmaxf(val, 0.0f);
        mx = fmaxf(mx, val);
    }
    feat[p] = mx;
}

__global__ void zero_kernel(float* p, int n) {
    int i = blockIdx.x * blockDim.x + threadIdx.x;
    if (i < n) p[i] = 0.f;
}

extern "C" void kernel_launch(void* const* d_in, const int* in_sizes, int n_in,
                              void* d_out, int out_size, void* d_ws, size_t ws_size,
                              hipStream_t stream) {
    (void)in_sizes; (void)n_in; (void)out_size; (void)ws_size;
    const float* xyz    = (const float*)d_in[0];
    const float* points = (const float*)d_in[1];
    const float* proj_w = (const float*)d_in[2];
    const float* proj_g = (const float*)d_in[3];
    const float* proj_b = (const float*)d_in[4];
    const float* w1     = (const float*)d_in[5];   // (2,64,64)
    const float* g1     = (const float*)d_in[6];
    const float* b1     = (const float*)d_in[7];
    const float* w2     = (const float*)d_in[8];
    const float* g2     = (const float*)d_in[9];
    const float* b2     = (const float*)d_in[10];

    float* out0 = (float*)d_out;                   // (4,3,2048)
    float* feat = (float*)d_out + NB * 3 * NPT;    // (4,64,2048)

    // Workspace layout: small arrays first, then TWO big tensors (A, B).
    // Total: (1024 + 262144 + 2*16777216) * 4 B = 135.3 MB.
    float* stats = (float*)d_ws;                    // 5 x 128 (rounded to 1024)
    int*   idx   = (int*)((float*)d_ws + 1024);     // (4,2048,32)
    float* A     = (float*)(idx + NB * NPT * KNB);  // activation tensor
    float* B     = A + TELEM;                       // residual tensor

    const size_t fps_lds = (size_t)(3 * NPTS) * sizeof(float)
                         + 2 * FWAVES * sizeof(unsigned long long);  // 98,432 B

    hipLaunchKernelGGL(zero_kernel, dim3(3), dim3(256), 0, stream, stats, 5 * 2 * CO);
    hipLaunchKernelGGL(fps_kernel, dim3(NB), dim3(FTHR), fps_lds, stream, xyz, out0);
    hipLaunchKernelGGL(ballq_kernel, dim3(2048), dim3(256), 0, stream, xyz, out0, idx);
    // proj raw conv -> A, stats0
    hipLaunchKernelGGL(proj_kernel, dim3(1024), dim3(256), 0, stream,
                       xyz, points, out0, idx, proj_w, A, stats);
    // d=0: x = relu(bnP(A)); idn0 -> B; y1 -> A (in-place)
    hipLaunchKernelGGL((conv_bn_kernel<false, true>), dim3(1024), dim3(256), 0, stream,
                       A, (const float*)nullptr, stats, proj_g, proj_b, w1,
                       B, A, stats + 128);
    // d=0: y2 = conv(w2[0], relu(bn1(y1)))  A -> A
    hipLaunchKernelGGL((conv_bn_kernel<false, false>), dim3(1024), dim3(256), 0, stream,
                       A, (const float*)nullptr, stats + 128, g1, b1, w2,
                       (float*)nullptr, A, stats + 256);
    // d=1: x = relu(bn2(y2)+idn0); idn1 -> B (aliases idn read); y1 -> A
    hipLaunchKernelGGL((conv_bn_kernel<true, true>), dim3(1024), dim3(256), 0, stream,
                       A, B, stats + 256, g2, b2, w1 + CO * CO,
                       B, A, stats + 384);
    // d=1: y2 = conv(w2[1], relu(bn1'(y1)))  A -> A
    hipLaunchKernelGGL((conv_bn_kernel<false, false>), dim3(1024), dim3(256), 0, stream,
                       A, (const float*)nullptr, stats + 384, g1 + CO, b1 + CO, w2 + CO * CO,
                       (float*)nullptr, A, stats + 512);
    // feat = max_k relu(bn2'(A)+B)
    hipLaunchKernelGGL(final_kernel, dim3(2048), dim3(256), 0, stream,
                       A, B, stats + 512, g2 + CO, b2 + CO, feat);
}